// Round 9
// baseline (329.704 us; speedup 1.0000x reference)
//
#include <hip/hip_runtime.h>

// PolyConv: h = sum_k theta[k] * L_sym^k x,  L_sym = I - D^{-1/2} A D^{-1/2}
// N=100000 nodes, E=1600000 edges, F=64 features, 5 theta terms.
//
// Round 9: (1) h deferred out of the gather passes -- each pass writes only
// bf16 f_k (separate buffers); a final streaming kernel combines
// h = th0*x + sum th_k*f_k. Removes 179MB of fp32 h traffic from the
// latency-bound gathers and halves their epilogue. (2) k_wtab removed:
// degree histogram fused into binA (global atomics, L2-resident 400KB),
// k_dinv converts, binB stores full int2{src,w} in one 8B write.

constexpr int kF = 64;
constexpr int BSHIFT = 8;             // bucket = dst >> 8  (256 nodes/bucket)
constexpr int NB = 1 << BSHIFT;       // 256 nodes per bucket
constexpr int TILE = 4096;            // edges per phase-A block
constexpr int KMAX = 512;             // array bound for K (=391)

static __device__ __forceinline__ float bfl(unsigned u) {        // low bf16 -> f32
    return __uint_as_float(u << 16);
}
static __device__ __forceinline__ float bfh(unsigned u) {        // high bf16 -> f32
    return __uint_as_float(u & 0xffff0000u);
}
static __device__ __forceinline__ unsigned f2bf(float f) {       // RNE f32 -> bf16
    unsigned u = __float_as_uint(f);
    return (u + 0x7fffu + ((u >> 16) & 1u)) >> 16;
}
static __device__ __forceinline__ unsigned pack2(float a, float b) {
    return f2bf(a) | (f2bf(b) << 16);
}

// Phase A: multisplit edges into K buckets (hist -> reserve -> direct global
// scatter with LDS cursors). Fused: per-node degree histogram (global
// atomics, 400KB L2-resident) and x (fp32) -> xb (bf16) conversion.
__global__ void k_binA(const int* __restrict__ src, const int* __restrict__ dst,
                       unsigned* __restrict__ pairs, int* __restrict__ gcursor,
                       int* __restrict__ deg,
                       const float4* __restrict__ x4, uint4* __restrict__ xb4,
                       int n8, int E, int K, int cap) {
    __shared__ int hist[KMAX];
    __shared__ int gb[KMAX];
    const int tid = threadIdx.x;        // blockDim = 512
    const long long tb = (long long)blockIdx.x * TILE;
    const int tcount = (int)min((long long)TILE, (long long)E - tb);

    // fused x -> bf16 convert (disjoint slice per block)
    {
        int per = (n8 + gridDim.x - 1) / (int)gridDim.x;
        int b0 = blockIdx.x * per;
        int b1 = min(b0 + per, n8);
        for (int i = b0 + tid; i < b1; i += 512) {
            float4 a = x4[2 * i];
            float4 b = x4[2 * i + 1];
            uint4 o;
            o.x = pack2(a.x, a.y);
            o.y = pack2(a.z, a.w);
            o.z = pack2(b.x, b.y);
            o.w = pack2(b.z, b.w);
            xb4[i] = o;
        }
    }

    hist[tid] = 0;
    __syncthreads();
    for (int i = tid; i < tcount; i += 512) {
        int d = dst[tb + i];
        atomicAdd(&hist[d >> BSHIFT], 1);
        atomicAdd(&deg[d], 1);           // global, L2-resident 400KB
    }
    __syncthreads();
    int hv = hist[tid];
    gb[tid] = (tid < K && hv > 0) ? atomicAdd(&gcursor[tid], hv) : 0;
    hist[tid] = 0;                       // reuse as local cursor
    __syncthreads();
    for (int i = tid; i < tcount; i += 512) {
        int d = dst[tb + i];
        int s = src[tb + i];
        int b = d >> BSHIFT;
        int pos = atomicAdd(&hist[b], 1);
        pairs[(size_t)b * cap + gb[b] + pos] =
            ((unsigned)(d & (NB - 1)) << 23) | (unsigned)s;
    }
}

// dinv[i] = rsqrt(max(deg[i],1))
__global__ void k_dinv(const int* __restrict__ deg, float* __restrict__ dinv, int n) {
    int i = blockIdx.x * blockDim.x + threadIdx.x;
    if (i < n) dinv[i] = rsqrtf(fmaxf((float)deg[i], 1.0f));
}

// Phase B: one block (512 threads) per bucket of 256 nodes (K=391 blocks).
// In-kernel gbase scan, per-node counts -> LDS scan -> scatter full
// int2{src, w=dinv[src]} (8B stores, bucket region ~32KB L2-resident),
// emits rp.
__global__ void k_binB(const unsigned* __restrict__ pairs, const int* __restrict__ gcursor,
                       const float* __restrict__ dinv, int* __restrict__ rp,
                       int2* __restrict__ ecsr, int N, int E, int K, int cap) {
    __shared__ int gsc[KMAX];
    __shared__ int cnt[NB];
    __shared__ int stmp[NB];
    __shared__ int excl[NB];
    __shared__ int cur[NB];
    const int b = blockIdx.x;
    const int tid = threadIdx.x;        // blockDim = 512

    int gv = (tid < K) ? gcursor[tid] : 0;
    gsc[tid] = gv;
    __syncthreads();
    for (int o = 1; o < KMAX; o <<= 1) {
        int t = (tid >= o) ? gsc[tid - o] : 0;
        __syncthreads();
        gsc[tid] += t;
        __syncthreads();
    }
    const int ecnt = gcursor[b];
    const int base = gsc[b] - ecnt;     // inclusive - own = exclusive
    const unsigned* bp = pairs + (size_t)b * cap;

    if (tid < NB) cnt[tid] = 0;
    __syncthreads();
    for (int i = tid; i < ecnt; i += 512)
        atomicAdd(&cnt[bp[i] >> 23], 1);
    __syncthreads();
    int v = (tid < NB) ? cnt[tid] : 0;
    if (tid < NB) stmp[tid] = v;
    __syncthreads();
    for (int o = 1; o < NB; o <<= 1) {
        int t = (tid >= o && tid < NB) ? stmp[tid - o] : 0;
        __syncthreads();
        if (tid < NB) stmp[tid] += t;
        __syncthreads();
    }
    if (tid < NB) {
        excl[tid] = stmp[tid] - v;
        cur[tid] = stmp[tid] - v;
    }
    __syncthreads();
    for (int i = tid; i < ecnt; i += 512) {
        unsigned p = bp[i];
        int s = (int)(p & 0x7FFFFFu);
        int pos = atomicAdd(&cur[p >> 23], 1);
        ecsr[base + pos] = make_int2(s, __float_as_int(dinv[s]));
    }
    int node = (b << BSHIFT) + tid;
    if (tid < NB && node < N) rp[node] = base + excl[tid];
    if (b == K - 1 && tid == 0) rp[N] = E;
}

// TWO nodes per wave, bf16 feature tables (128B rows), K-loop unrolled x2.
// Lane l: half = l>>5, r = (l>>3)&3, c = l&7 (16B = 8 features).
// Per edge: one streaming 8B (src,w) load + one dependent 128B row gather.
// Butterfly over lanes ^8,^16 leaves lanes {0..7, 32..39} complete.
// Epilogue: featout[d] = bf16(featin[d] - dinv[d]*acc).  (h deferred)
__global__ void k_gather(const int* __restrict__ rp, const int2* __restrict__ ecsr,
                         const unsigned short* __restrict__ featin,
                         const float* __restrict__ dinv,
                         unsigned short* __restrict__ featout, int n) {
    int wid = (blockIdx.x * blockDim.x + threadIdx.x) >> 6;
    int lane = threadIdx.x & 63;
    int half = lane >> 5;
    int r = (lane >> 3) & 3;
    int c = lane & 7;
    int node = wid * 2 + half;
    if (wid * 2 >= n) return;
    bool valid = node < n;
    int beg = valid ? rp[node] : 0;
    int end = valid ? rp[node + 1] : 0;
    int len = end - beg;
    int olen = __shfl_xor(len, 32, 64);
    int mlen = (len > olen) ? len : olen;   // pair max -> uniform trip count

    float acc[8] = {0.f, 0.f, 0.f, 0.f, 0.f, 0.f, 0.f, 0.f};
    for (int i = 0; i < mlen; i += 8) {
        int j1 = beg + i + r;
        int j2 = j1 + 4;
        bool ok1 = j1 < end;
        bool ok2 = j2 < end;
        int2 e1 = ecsr[ok1 ? j1 : 0];
        int2 e2 = ecsr[ok2 ? j2 : 0];
        int s1 = e1.x;
        int s2 = e2.x;
        float w1 = ok1 ? __int_as_float(e1.y) : 0.0f;
        float w2 = ok2 ? __int_as_float(e2.y) : 0.0f;
        uint4 ra = *(const uint4*)(featin + ((size_t)s1 << 6) + (c << 3));
        uint4 rb = *(const uint4*)(featin + ((size_t)s2 << 6) + (c << 3));
        acc[0] += w1 * bfl(ra.x);
        acc[1] += w1 * bfh(ra.x);
        acc[2] += w1 * bfl(ra.y);
        acc[3] += w1 * bfh(ra.y);
        acc[4] += w1 * bfl(ra.z);
        acc[5] += w1 * bfh(ra.z);
        acc[6] += w1 * bfl(ra.w);
        acc[7] += w1 * bfh(ra.w);
        acc[0] += w2 * bfl(rb.x);
        acc[1] += w2 * bfh(rb.x);
        acc[2] += w2 * bfl(rb.y);
        acc[3] += w2 * bfh(rb.y);
        acc[4] += w2 * bfl(rb.z);
        acc[5] += w2 * bfh(rb.z);
        acc[6] += w2 * bfl(rb.w);
        acc[7] += w2 * bfh(rb.w);
    }
    #pragma unroll
    for (int m = 8; m <= 16; m <<= 1) {
        #pragma unroll
        for (int i = 0; i < 8; ++i)
            acc[i] += __shfl_xor(acc[i], m, 64);
    }

    if (r == 0 && valid) {                   // lanes 0..7 and 32..39
        size_t off = ((size_t)node << 6) + (c << 3);
        uint4 rr = *(const uint4*)(featin + off);
        float di = dinv[node];
        uint4 o;
        o.x = pack2(bfl(rr.x) - di * acc[0], bfh(rr.x) - di * acc[1]);
        o.y = pack2(bfl(rr.y) - di * acc[2], bfh(rr.y) - di * acc[3]);
        o.z = pack2(bfl(rr.z) - di * acc[4], bfh(rr.z) - di * acc[5]);
        o.w = pack2(bfl(rr.w) - di * acc[6], bfh(rr.w) - di * acc[7]);
        *(uint4*)(featout + off) = o;
    }
}

// h = th0*x + th1*f1 + th2*f2 + th3*f3 + th4*f4   (8 elements per thread)
__global__ void k_final(const float4* __restrict__ x4,
                        const uint4* __restrict__ f1, const uint4* __restrict__ f2,
                        const uint4* __restrict__ f3, const uint4* __restrict__ f4,
                        float4* __restrict__ h4, int n8,
                        float t0, float t1, float t2, float t3, float t4) {
    int i = blockIdx.x * blockDim.x + threadIdx.x;
    if (i >= n8) return;
    uint4 a = f1[i], b = f2[i], cc = f3[i], d = f4[i];
    float4 xa = x4[2 * i], xb = x4[2 * i + 1];
    float4 h0, h1;
    h0.x = t0 * xa.x + t1 * bfl(a.x) + t2 * bfl(b.x) + t3 * bfl(cc.x) + t4 * bfl(d.x);
    h0.y = t0 * xa.y + t1 * bfh(a.x) + t2 * bfh(b.x) + t3 * bfh(cc.x) + t4 * bfh(d.x);
    h0.z = t0 * xa.z + t1 * bfl(a.y) + t2 * bfl(b.y) + t3 * bfl(cc.y) + t4 * bfl(d.y);
    h0.w = t0 * xa.w + t1 * bfh(a.y) + t2 * bfh(b.y) + t3 * bfh(cc.y) + t4 * bfh(d.y);
    h1.x = t0 * xb.x + t1 * bfl(a.z) + t2 * bfl(b.z) + t3 * bfl(cc.z) + t4 * bfl(d.z);
    h1.y = t0 * xb.y + t1 * bfh(a.z) + t2 * bfh(b.z) + t3 * bfh(cc.z) + t4 * bfh(d.z);
    h1.z = t0 * xb.z + t1 * bfl(a.w) + t2 * bfl(b.w) + t3 * bfl(cc.w) + t4 * bfl(d.w);
    h1.w = t0 * xb.w + t1 * bfh(a.w) + t2 * bfh(b.w) + t3 * bfh(cc.w) + t4 * bfh(d.w);
    h4[2 * i] = h0;
    h4[2 * i + 1] = h1;
}

extern "C" void kernel_launch(void* const* d_in, const int* in_sizes, int n_in,
                              void* d_out, int out_size, void* d_ws, size_t ws_size,
                              hipStream_t stream) {
    const float* x  = (const float*)d_in[0];
    const int*   ei = (const int*)d_in[1];   // edge_index [2, E] row-major
    const int N = in_sizes[0] / kF;
    const int E = in_sizes[1] / 2;
    const int* src = ei;
    const int* dst = ei + E;
    float* h = (float*)d_out;

    const int K = (N + NB - 1) >> BSHIFT;         // 391 buckets (K <= KMAX)
    const int cap = 2 * ((E + K - 1) / K);        // per-bucket capacity

    // workspace (~85 MB): gcursor | deg | rp | dinv | ecsr | xb | f1..f4 | pairs
    char* ws = (char*)d_ws;
    size_t off = 0;
    auto carve = [&](size_t bytes) {
        void* p = ws + off;
        off = (off + bytes + 511) & ~(size_t)511;
        return p;
    };
    int*            gcursor = (int*)carve((size_t)K * 4);
    int*            deg     = (int*)carve((size_t)N * 4);
    int*            rp      = (int*)carve((size_t)(N + 1) * 4);
    float*          dinv    = (float*)carve((size_t)N * 4);
    int2*           ecsr    = (int2*)carve((size_t)E * 8);
    unsigned short* xb      = (unsigned short*)carve((size_t)N * kF * 2);
    unsigned short* f1      = (unsigned short*)carve((size_t)N * kF * 2);
    unsigned short* f2      = (unsigned short*)carve((size_t)N * kF * 2);
    unsigned short* f3      = (unsigned short*)carve((size_t)N * kF * 2);
    unsigned short* f4      = (unsigned short*)carve((size_t)N * kF * 2);
    unsigned*       pairs   = (unsigned*)carve((size_t)K * cap * 4);

    const float theta[5] = {0.6f, -0.4f, 0.3f, -0.2f, 0.1f};
    const int n8 = N * kF / 8;

    // ---- CSR build (multisplit) with fused degree + x->bf16 convert ----
    hipMemsetAsync(gcursor, 0, (size_t)K * 4, stream);
    hipMemsetAsync(deg, 0, (size_t)N * 4, stream);
    k_binA<<<(E + TILE - 1) / TILE, 512, 0, stream>>>(src, dst, pairs, gcursor, deg,
                                                      (const float4*)x, (uint4*)xb,
                                                      n8, E, K, cap);
    k_dinv<<<(N + 511) / 512, 512, 0, stream>>>(deg, dinv, N);
    k_binB<<<K, 512, 0, stream>>>(pairs, gcursor, dinv, rp, ecsr, N, E, K, cap);

    // ---- 4 gather passes: f_k = L_sym f_{k-1} (bf16 in/out, h deferred) ----
    const int nwaves = (N + 1) / 2;                // 2 nodes per wave
    const int gblocks = (nwaves + 3) / 4;          // 4 waves per 256-thread block
    k_gather<<<gblocks, 256, 0, stream>>>(rp, ecsr, xb, dinv, f1, N);
    k_gather<<<gblocks, 256, 0, stream>>>(rp, ecsr, f1, dinv, f2, N);
    k_gather<<<gblocks, 256, 0, stream>>>(rp, ecsr, f2, dinv, f3, N);
    k_gather<<<gblocks, 256, 0, stream>>>(rp, ecsr, f3, dinv, f4, N);

    // ---- h = th0*x + sum th_k*f_k (streaming) ----
    k_final<<<(n8 + 255) / 256, 256, 0, stream>>>((const float4*)x,
                                                  (const uint4*)f1, (const uint4*)f2,
                                                  (const uint4*)f3, (const uint4*)f4,
                                                  (float4*)h, n8,
                                                  theta[0], theta[1], theta[2],
                                                  theta[3], theta[4]);
}

// Round 10
// 274.582 us; speedup vs baseline: 1.2007x; 1.2007x over previous
//
#include <hip/hip_runtime.h>

// PolyConv: h = sum_k theta[k] * L_sym^k x,  L_sym = I - D^{-1/2} A D^{-1/2}
// N=100000 nodes, E=1600000 edges, F=64 features, 5 theta terms.
//
// Round 10: revert r9's per-edge global deg atomics (write-through line
// amplification made binA 88us). Degrees come free from binB's per-bucket
// counts. binB split: binB1 = count+scan -> rp + dinv; binB2 = rebuild
// cursors from rp, scatter int2{src, dinv[src]} in one 8B store. Keeps r9's
// h-deferral (gathers write bf16 f_k only; k_final combines).

constexpr int kF = 64;
constexpr int BSHIFT = 8;             // bucket = dst >> 8  (256 nodes/bucket)
constexpr int NB = 1 << BSHIFT;       // 256 nodes per bucket
constexpr int TILE = 4096;            // edges per phase-A block
constexpr int KMAX = 512;             // array bound for K (=391)

static __device__ __forceinline__ float bfl(unsigned u) {        // low bf16 -> f32
    return __uint_as_float(u << 16);
}
static __device__ __forceinline__ float bfh(unsigned u) {        // high bf16 -> f32
    return __uint_as_float(u & 0xffff0000u);
}
static __device__ __forceinline__ unsigned f2bf(float f) {       // RNE f32 -> bf16
    unsigned u = __float_as_uint(f);
    return (u + 0x7fffu + ((u >> 16) & 1u)) >> 16;
}
static __device__ __forceinline__ unsigned pack2(float a, float b) {
    return f2bf(a) | (f2bf(b) << 16);
}

// Phase A: multisplit edges into K buckets (hist -> reserve -> direct global
// scatter with LDS cursors). Fused x (fp32) -> xb (bf16) conversion.
__global__ void k_binA(const int* __restrict__ src, const int* __restrict__ dst,
                       unsigned* __restrict__ pairs, int* __restrict__ gcursor,
                       const float4* __restrict__ x4, uint4* __restrict__ xb4,
                       int n8, int E, int K, int cap) {
    __shared__ int hist[KMAX];
    __shared__ int gb[KMAX];
    const int tid = threadIdx.x;        // blockDim = 512
    const long long tb = (long long)blockIdx.x * TILE;
    const int tcount = (int)min((long long)TILE, (long long)E - tb);

    // fused x -> bf16 convert (disjoint slice per block)
    {
        int per = (n8 + gridDim.x - 1) / (int)gridDim.x;
        int b0 = blockIdx.x * per;
        int b1 = min(b0 + per, n8);
        for (int i = b0 + tid; i < b1; i += 512) {
            float4 a = x4[2 * i];
            float4 b = x4[2 * i + 1];
            uint4 o;
            o.x = pack2(a.x, a.y);
            o.y = pack2(a.z, a.w);
            o.z = pack2(b.x, b.y);
            o.w = pack2(b.z, b.w);
            xb4[i] = o;
        }
    }

    hist[tid] = 0;
    __syncthreads();
    for (int i = tid; i < tcount; i += 512)
        atomicAdd(&hist[dst[tb + i] >> BSHIFT], 1);
    __syncthreads();
    int hv = hist[tid];
    gb[tid] = (tid < K && hv > 0) ? atomicAdd(&gcursor[tid], hv) : 0;
    hist[tid] = 0;                       // reuse as local cursor
    __syncthreads();
    for (int i = tid; i < tcount; i += 512) {
        int d = dst[tb + i];
        int s = src[tb + i];
        int b = d >> BSHIFT;
        int pos = atomicAdd(&hist[b], 1);
        pairs[(size_t)b * cap + gb[b] + pos] =
            ((unsigned)(d & (NB - 1)) << 23) | (unsigned)s;
    }
}

// Phase B1: one block per bucket. Per-node counts (== in-degree) -> scan ->
// rp + dinv for the bucket's 256 nodes. In-kernel gbase scan over gcursor.
__global__ void k_binB1(const unsigned* __restrict__ pairs, const int* __restrict__ gcursor,
                        int* __restrict__ rp, float* __restrict__ dinv,
                        int N, int E, int K, int cap) {
    __shared__ int gsc[KMAX];
    __shared__ int cnt[NB];
    __shared__ int stmp[NB];
    const int b = blockIdx.x;
    const int tid = threadIdx.x;        // blockDim = 512

    int gv = (tid < K) ? gcursor[tid] : 0;
    gsc[tid] = gv;
    __syncthreads();
    for (int o = 1; o < KMAX; o <<= 1) {
        int t = (tid >= o) ? gsc[tid - o] : 0;
        __syncthreads();
        gsc[tid] += t;
        __syncthreads();
    }
    const int ecnt = gcursor[b];
    const int base = gsc[b] - ecnt;     // inclusive - own = exclusive
    const unsigned* bp = pairs + (size_t)b * cap;

    if (tid < NB) cnt[tid] = 0;
    __syncthreads();
    for (int i = tid; i < ecnt; i += 512)
        atomicAdd(&cnt[bp[i] >> 23], 1);
    __syncthreads();
    int v = (tid < NB) ? cnt[tid] : 0;
    if (tid < NB) stmp[tid] = v;
    __syncthreads();
    for (int o = 1; o < NB; o <<= 1) {
        int t = (tid >= o && tid < NB) ? stmp[tid - o] : 0;
        __syncthreads();
        if (tid < NB) stmp[tid] += t;
        __syncthreads();
    }
    int node = (b << BSHIFT) + tid;
    if (tid < NB && node < N) {
        rp[node] = base + stmp[tid] - v;            // exclusive
        dinv[node] = rsqrtf(fmaxf((float)v, 1.0f)); // cnt == in-degree
    }
    if (b == K - 1 && tid == 0) rp[N] = E;
}

// Phase B2: one block per bucket. Cursors rebuilt straight from rp (absolute
// csr offsets), then scatter int2{src, w=dinv[src]} in one 8B store.
// dinv (400KB) is L2/LLC-hot random read. Bucket's ecsr region ~32KB.
__global__ void k_binB2(const unsigned* __restrict__ pairs, const int* __restrict__ gcursor,
                        const int* __restrict__ rp, const float* __restrict__ dinv,
                        int2* __restrict__ ecsr, int N, int K, int cap) {
    __shared__ int cur[NB];
    const int b = blockIdx.x;
    const int tid = threadIdx.x;        // blockDim = 512
    const int ecnt = gcursor[b];
    const unsigned* bp = pairs + (size_t)b * cap;

    int node = (b << BSHIFT) + tid;
    if (tid < NB) cur[tid] = (node < N) ? rp[node] : 0;
    __syncthreads();
    for (int i = tid; i < ecnt; i += 512) {
        unsigned p = bp[i];
        int s = (int)(p & 0x7FFFFFu);
        int pos = atomicAdd(&cur[p >> 23], 1);      // absolute csr index
        ecsr[pos] = make_int2(s, __float_as_int(dinv[s]));
    }
}

// TWO nodes per wave, bf16 feature tables (128B rows), K-loop unrolled x2.
// Lane l: half = l>>5, r = (l>>3)&3, c = l&7 (16B = 8 features).
// Per edge: one streaming 8B (src,w) load + one dependent 128B row gather.
// Butterfly over lanes ^8,^16 leaves lanes {0..7, 32..39} complete.
// Epilogue: featout[d] = bf16(featin[d] - dinv[d]*acc).  (h deferred)
__global__ void k_gather(const int* __restrict__ rp, const int2* __restrict__ ecsr,
                         const unsigned short* __restrict__ featin,
                         const float* __restrict__ dinv,
                         unsigned short* __restrict__ featout, int n) {
    int wid = (blockIdx.x * blockDim.x + threadIdx.x) >> 6;
    int lane = threadIdx.x & 63;
    int half = lane >> 5;
    int r = (lane >> 3) & 3;
    int c = lane & 7;
    int node = wid * 2 + half;
    if (wid * 2 >= n) return;
    bool valid = node < n;
    int beg = valid ? rp[node] : 0;
    int end = valid ? rp[node + 1] : 0;
    int len = end - beg;
    int olen = __shfl_xor(len, 32, 64);
    int mlen = (len > olen) ? len : olen;   // pair max -> uniform trip count

    float acc[8] = {0.f, 0.f, 0.f, 0.f, 0.f, 0.f, 0.f, 0.f};
    for (int i = 0; i < mlen; i += 8) {
        int j1 = beg + i + r;
        int j2 = j1 + 4;
        bool ok1 = j1 < end;
        bool ok2 = j2 < end;
        int2 e1 = ecsr[ok1 ? j1 : 0];
        int2 e2 = ecsr[ok2 ? j2 : 0];
        int s1 = e1.x;
        int s2 = e2.x;
        float w1 = ok1 ? __int_as_float(e1.y) : 0.0f;
        float w2 = ok2 ? __int_as_float(e2.y) : 0.0f;
        uint4 ra = *(const uint4*)(featin + ((size_t)s1 << 6) + (c << 3));
        uint4 rb = *(const uint4*)(featin + ((size_t)s2 << 6) + (c << 3));
        acc[0] += w1 * bfl(ra.x);
        acc[1] += w1 * bfh(ra.x);
        acc[2] += w1 * bfl(ra.y);
        acc[3] += w1 * bfh(ra.y);
        acc[4] += w1 * bfl(ra.z);
        acc[5] += w1 * bfh(ra.z);
        acc[6] += w1 * bfl(ra.w);
        acc[7] += w1 * bfh(ra.w);
        acc[0] += w2 * bfl(rb.x);
        acc[1] += w2 * bfh(rb.x);
        acc[2] += w2 * bfl(rb.y);
        acc[3] += w2 * bfh(rb.y);
        acc[4] += w2 * bfl(rb.z);
        acc[5] += w2 * bfh(rb.z);
        acc[6] += w2 * bfl(rb.w);
        acc[7] += w2 * bfh(rb.w);
    }
    #pragma unroll
    for (int m = 8; m <= 16; m <<= 1) {
        #pragma unroll
        for (int i = 0; i < 8; ++i)
            acc[i] += __shfl_xor(acc[i], m, 64);
    }

    if (r == 0 && valid) {                   // lanes 0..7 and 32..39
        size_t off = ((size_t)node << 6) + (c << 3);
        uint4 rr = *(const uint4*)(featin + off);
        float di = dinv[node];
        uint4 o;
        o.x = pack2(bfl(rr.x) - di * acc[0], bfh(rr.x) - di * acc[1]);
        o.y = pack2(bfl(rr.y) - di * acc[2], bfh(rr.y) - di * acc[3]);
        o.z = pack2(bfl(rr.z) - di * acc[4], bfh(rr.z) - di * acc[5]);
        o.w = pack2(bfl(rr.w) - di * acc[6], bfh(rr.w) - di * acc[7]);
        *(uint4*)(featout + off) = o;
    }
}

// h = th0*x + th1*f1 + th2*f2 + th3*f3 + th4*f4   (8 elements per thread)
__global__ void k_final(const float4* __restrict__ x4,
                        const uint4* __restrict__ f1, const uint4* __restrict__ f2,
                        const uint4* __restrict__ f3, const uint4* __restrict__ f4,
                        float4* __restrict__ h4, int n8,
                        float t0, float t1, float t2, float t3, float t4) {
    int i = blockIdx.x * blockDim.x + threadIdx.x;
    if (i >= n8) return;
    uint4 a = f1[i], b = f2[i], cc = f3[i], d = f4[i];
    float4 xa = x4[2 * i], xb = x4[2 * i + 1];
    float4 h0, h1;
    h0.x = t0 * xa.x + t1 * bfl(a.x) + t2 * bfl(b.x) + t3 * bfl(cc.x) + t4 * bfl(d.x);
    h0.y = t0 * xa.y + t1 * bfh(a.x) + t2 * bfh(b.x) + t3 * bfh(cc.x) + t4 * bfh(d.x);
    h0.z = t0 * xa.z + t1 * bfl(a.y) + t2 * bfl(b.y) + t3 * bfl(cc.y) + t4 * bfl(d.y);
    h0.w = t0 * xa.w + t1 * bfh(a.y) + t2 * bfh(b.y) + t3 * bfh(cc.y) + t4 * bfh(d.y);
    h1.x = t0 * xb.x + t1 * bfl(a.z) + t2 * bfl(b.z) + t3 * bfl(cc.z) + t4 * bfl(d.z);
    h1.y = t0 * xb.y + t1 * bfh(a.z) + t2 * bfh(b.z) + t3 * bfh(cc.z) + t4 * bfh(d.z);
    h1.z = t0 * xb.z + t1 * bfl(a.w) + t2 * bfl(b.w) + t3 * bfl(cc.w) + t4 * bfl(d.w);
    h1.w = t0 * xb.w + t1 * bfh(a.w) + t2 * bfh(b.w) + t3 * bfh(cc.w) + t4 * bfh(d.w);
    h4[2 * i] = h0;
    h4[2 * i + 1] = h1;
}

extern "C" void kernel_launch(void* const* d_in, const int* in_sizes, int n_in,
                              void* d_out, int out_size, void* d_ws, size_t ws_size,
                              hipStream_t stream) {
    const float* x  = (const float*)d_in[0];
    const int*   ei = (const int*)d_in[1];   // edge_index [2, E] row-major
    const int N = in_sizes[0] / kF;
    const int E = in_sizes[1] / 2;
    const int* src = ei;
    const int* dst = ei + E;
    float* h = (float*)d_out;

    const int K = (N + NB - 1) >> BSHIFT;         // 391 buckets (K <= KMAX)
    const int cap = 2 * ((E + K - 1) / K);        // per-bucket capacity

    // workspace (~85 MB): gcursor | rp | dinv | ecsr | xb | f1..f4 | pairs
    char* ws = (char*)d_ws;
    size_t off = 0;
    auto carve = [&](size_t bytes) {
        void* p = ws + off;
        off = (off + bytes + 511) & ~(size_t)511;
        return p;
    };
    int*            gcursor = (int*)carve((size_t)K * 4);
    int*            rp      = (int*)carve((size_t)(N + 1) * 4);
    float*          dinv    = (float*)carve((size_t)N * 4);
    int2*           ecsr    = (int2*)carve((size_t)E * 8);
    unsigned short* xb      = (unsigned short*)carve((size_t)N * kF * 2);
    unsigned short* f1      = (unsigned short*)carve((size_t)N * kF * 2);
    unsigned short* f2      = (unsigned short*)carve((size_t)N * kF * 2);
    unsigned short* f3      = (unsigned short*)carve((size_t)N * kF * 2);
    unsigned short* f4      = (unsigned short*)carve((size_t)N * kF * 2);
    unsigned*       pairs   = (unsigned*)carve((size_t)K * cap * 4);

    const float theta[5] = {0.6f, -0.4f, 0.3f, -0.2f, 0.1f};
    const int n8 = N * kF / 8;

    // ---- CSR build (multisplit) with fused x->bf16 convert ----
    hipMemsetAsync(gcursor, 0, (size_t)K * 4, stream);
    k_binA<<<(E + TILE - 1) / TILE, 512, 0, stream>>>(src, dst, pairs, gcursor,
                                                      (const float4*)x, (uint4*)xb,
                                                      n8, E, K, cap);
    k_binB1<<<K, 512, 0, stream>>>(pairs, gcursor, rp, dinv, N, E, K, cap);
    k_binB2<<<K, 512, 0, stream>>>(pairs, gcursor, rp, dinv, ecsr, N, K, cap);

    // ---- 4 gather passes: f_k = L_sym f_{k-1} (bf16 in/out, h deferred) ----
    const int nwaves = (N + 1) / 2;                // 2 nodes per wave
    const int gblocks = (nwaves + 3) / 4;          // 4 waves per 256-thread block
    k_gather<<<gblocks, 256, 0, stream>>>(rp, ecsr, xb, dinv, f1, N);
    k_gather<<<gblocks, 256, 0, stream>>>(rp, ecsr, f1, dinv, f2, N);
    k_gather<<<gblocks, 256, 0, stream>>>(rp, ecsr, f2, dinv, f3, N);
    k_gather<<<gblocks, 256, 0, stream>>>(rp, ecsr, f3, dinv, f4, N);

    // ---- h = th0*x + sum th_k*f_k (streaming) ----
    k_final<<<(n8 + 255) / 256, 256, 0, stream>>>((const float4*)x,
                                                  (const uint4*)f1, (const uint4*)f2,
                                                  (const uint4*)f3, (const uint4*)f4,
                                                  (float4*)h, n8,
                                                  theta[0], theta[1], theta[2],
                                                  theta[3], theta[4]);
}

// Round 11
// 268.008 us; speedup vs baseline: 1.2302x; 1.0245x over previous
//
#include <hip/hip_runtime.h>

// PolyConv: h = sum_k theta[k] * L_sym^k x,  L_sym = I - D^{-1/2} A D^{-1/2}
// N=100000 nodes, E=1600000 edges, F=64 features, 5 theta terms.
//
// Round 11: (1) gather K-loop unrolled x4 -- 4 independent 128B row gathers
// in flight per wave-iteration (was pinned at the outstanding-request limit:
// ~5KB in flight/CU vs ~6KB needed at 600cyc latency); (2) binA TILE
// 4096->2048 (782 blocks, was 1.5 blocks/CU latency-starved) + dst/src
// register-cached across phases (one streaming read); (3) k_final reads
// bf16 xb (saves 12.8MB).

constexpr int kF = 64;
constexpr int BSHIFT = 8;             // bucket = dst >> 8  (256 nodes/bucket)
constexpr int NB = 1 << BSHIFT;       // 256 nodes per bucket
constexpr int TILE = 2048;            // edges per phase-A block (4/thread)
constexpr int KMAX = 512;             // array bound for K (=391)

static __device__ __forceinline__ float bfl(unsigned u) {        // low bf16 -> f32
    return __uint_as_float(u << 16);
}
static __device__ __forceinline__ float bfh(unsigned u) {        // high bf16 -> f32
    return __uint_as_float(u & 0xffff0000u);
}
static __device__ __forceinline__ unsigned f2bf(float f) {       // RNE f32 -> bf16
    unsigned u = __float_as_uint(f);
    return (u + 0x7fffu + ((u >> 16) & 1u)) >> 16;
}
static __device__ __forceinline__ unsigned pack2(float a, float b) {
    return f2bf(a) | (f2bf(b) << 16);
}

// Phase A: multisplit edges into K buckets (hist -> reserve -> direct global
// scatter with LDS cursors). dst/src cached in registers across the two
// phases. Fused x (fp32) -> xb (bf16) conversion.
__global__ void k_binA(const int* __restrict__ src, const int* __restrict__ dst,
                       unsigned* __restrict__ pairs, int* __restrict__ gcursor,
                       const float4* __restrict__ x4, uint4* __restrict__ xb4,
                       int n8, int E, int K, int cap) {
    __shared__ int hist[KMAX];
    __shared__ int gb[KMAX];
    const int tid = threadIdx.x;        // blockDim = 512
    const long long tb = (long long)blockIdx.x * TILE;
    const int tcount = (int)min((long long)TILE, (long long)E - tb);

    // fused x -> bf16 convert (disjoint slice per block)
    {
        int per = (n8 + gridDim.x - 1) / (int)gridDim.x;
        int b0 = blockIdx.x * per;
        int b1 = min(b0 + per, n8);
        for (int i = b0 + tid; i < b1; i += 512) {
            float4 a = x4[2 * i];
            float4 b = x4[2 * i + 1];
            uint4 o;
            o.x = pack2(a.x, a.y);
            o.y = pack2(a.z, a.w);
            o.z = pack2(b.x, b.y);
            o.w = pack2(b.z, b.w);
            xb4[i] = o;
        }
    }

    hist[tid] = 0;
    __syncthreads();
    int dc[4], sc[4];
    #pragma unroll
    for (int k = 0; k < 4; ++k) {
        int i = tid + k * 512;
        if (i < tcount) {
            dc[k] = dst[tb + i];
            sc[k] = src[tb + i];
            atomicAdd(&hist[dc[k] >> BSHIFT], 1);
        } else {
            dc[k] = -1;
        }
    }
    __syncthreads();
    int hv = hist[tid];
    gb[tid] = (tid < K && hv > 0) ? atomicAdd(&gcursor[tid], hv) : 0;
    hist[tid] = 0;                       // reuse as local cursor
    __syncthreads();
    #pragma unroll
    for (int k = 0; k < 4; ++k) {
        if (dc[k] >= 0) {
            int d = dc[k];
            int b = d >> BSHIFT;
            int pos = atomicAdd(&hist[b], 1);
            pairs[(size_t)b * cap + gb[b] + pos] =
                ((unsigned)(d & (NB - 1)) << 23) | (unsigned)sc[k];
        }
    }
}

// Phase B1: one block per bucket. Per-node counts (== in-degree) -> scan ->
// rp + dinv for the bucket's 256 nodes. In-kernel gbase scan over gcursor.
__global__ void k_binB1(const unsigned* __restrict__ pairs, const int* __restrict__ gcursor,
                        int* __restrict__ rp, float* __restrict__ dinv,
                        int N, int E, int K, int cap) {
    __shared__ int gsc[KMAX];
    __shared__ int cnt[NB];
    __shared__ int stmp[NB];
    const int b = blockIdx.x;
    const int tid = threadIdx.x;        // blockDim = 512

    int gv = (tid < K) ? gcursor[tid] : 0;
    gsc[tid] = gv;
    __syncthreads();
    for (int o = 1; o < KMAX; o <<= 1) {
        int t = (tid >= o) ? gsc[tid - o] : 0;
        __syncthreads();
        gsc[tid] += t;
        __syncthreads();
    }
    const int ecnt = gcursor[b];
    const int base = gsc[b] - ecnt;     // inclusive - own = exclusive
    const unsigned* bp = pairs + (size_t)b * cap;

    if (tid < NB) cnt[tid] = 0;
    __syncthreads();
    for (int i = tid; i < ecnt; i += 512)
        atomicAdd(&cnt[bp[i] >> 23], 1);
    __syncthreads();
    int v = (tid < NB) ? cnt[tid] : 0;
    if (tid < NB) stmp[tid] = v;
    __syncthreads();
    for (int o = 1; o < NB; o <<= 1) {
        int t = (tid >= o && tid < NB) ? stmp[tid - o] : 0;
        __syncthreads();
        if (tid < NB) stmp[tid] += t;
        __syncthreads();
    }
    int node = (b << BSHIFT) + tid;
    if (tid < NB && node < N) {
        rp[node] = base + stmp[tid] - v;            // exclusive
        dinv[node] = rsqrtf(fmaxf((float)v, 1.0f)); // cnt == in-degree
    }
    if (b == K - 1 && tid == 0) rp[N] = E;
}

// Phase B2: one block per bucket. Cursors rebuilt straight from rp (absolute
// csr offsets), then scatter int2{src, w=dinv[src]} in one 8B store.
// dinv (400KB) is L2/LLC-hot random read. Bucket's ecsr region ~32KB.
__global__ void k_binB2(const unsigned* __restrict__ pairs, const int* __restrict__ gcursor,
                        const int* __restrict__ rp, const float* __restrict__ dinv,
                        int2* __restrict__ ecsr, int N, int K, int cap) {
    __shared__ int cur[NB];
    const int b = blockIdx.x;
    const int tid = threadIdx.x;        // blockDim = 512
    const int ecnt = gcursor[b];
    const unsigned* bp = pairs + (size_t)b * cap;

    int node = (b << BSHIFT) + tid;
    if (tid < NB) cur[tid] = (node < N) ? rp[node] : 0;
    __syncthreads();
    for (int i = tid; i < ecnt; i += 512) {
        unsigned p = bp[i];
        int s = (int)(p & 0x7FFFFFu);
        int pos = atomicAdd(&cur[p >> 23], 1);      // absolute csr index
        ecsr[pos] = make_int2(s, __float_as_int(dinv[s]));
    }
}

// TWO nodes per wave, bf16 feature tables (128B rows), K-loop unrolled x4.
// Lane l: half = l>>5, r = (l>>3)&3, c = l&7 (16B = 8 features).
// Per iteration: 4 independent (8B ecsr + dependent 128B row) chains in
// flight per lane. Butterfly over lanes ^8,^16 leaves lanes {0..7, 32..39}
// complete. Epilogue: featout[d] = bf16(featin[d] - dinv[d]*acc).
__global__ void k_gather(const int* __restrict__ rp, const int2* __restrict__ ecsr,
                         const unsigned short* __restrict__ featin,
                         const float* __restrict__ dinv,
                         unsigned short* __restrict__ featout, int n) {
    int wid = (blockIdx.x * blockDim.x + threadIdx.x) >> 6;
    int lane = threadIdx.x & 63;
    int half = lane >> 5;
    int r = (lane >> 3) & 3;
    int c = lane & 7;
    int node = wid * 2 + half;
    if (wid * 2 >= n) return;
    bool valid = node < n;
    int beg = valid ? rp[node] : 0;
    int end = valid ? rp[node + 1] : 0;
    int len = end - beg;
    int olen = __shfl_xor(len, 32, 64);
    int mlen = (len > olen) ? len : olen;   // pair max -> uniform trip count

    float acc[8] = {0.f, 0.f, 0.f, 0.f, 0.f, 0.f, 0.f, 0.f};
    for (int i = 0; i < mlen; i += 16) {
        int j1 = beg + i + r;
        int j2 = j1 + 4;
        int j3 = j1 + 8;
        int j4 = j1 + 12;
        bool ok1 = j1 < end, ok2 = j2 < end, ok3 = j3 < end, ok4 = j4 < end;
        int2 e1 = ecsr[ok1 ? j1 : 0];
        int2 e2 = ecsr[ok2 ? j2 : 0];
        int2 e3 = ecsr[ok3 ? j3 : 0];
        int2 e4 = ecsr[ok4 ? j4 : 0];
        float w1 = ok1 ? __int_as_float(e1.y) : 0.0f;
        float w2 = ok2 ? __int_as_float(e2.y) : 0.0f;
        float w3 = ok3 ? __int_as_float(e3.y) : 0.0f;
        float w4 = ok4 ? __int_as_float(e4.y) : 0.0f;
        uint4 ra = *(const uint4*)(featin + ((size_t)e1.x << 6) + (c << 3));
        uint4 rb = *(const uint4*)(featin + ((size_t)e2.x << 6) + (c << 3));
        uint4 rc = *(const uint4*)(featin + ((size_t)e3.x << 6) + (c << 3));
        uint4 rd = *(const uint4*)(featin + ((size_t)e4.x << 6) + (c << 3));
        acc[0] += w1 * bfl(ra.x); acc[1] += w1 * bfh(ra.x);
        acc[2] += w1 * bfl(ra.y); acc[3] += w1 * bfh(ra.y);
        acc[4] += w1 * bfl(ra.z); acc[5] += w1 * bfh(ra.z);
        acc[6] += w1 * bfl(ra.w); acc[7] += w1 * bfh(ra.w);
        acc[0] += w2 * bfl(rb.x); acc[1] += w2 * bfh(rb.x);
        acc[2] += w2 * bfl(rb.y); acc[3] += w2 * bfh(rb.y);
        acc[4] += w2 * bfl(rb.z); acc[5] += w2 * bfh(rb.z);
        acc[6] += w2 * bfl(rb.w); acc[7] += w2 * bfh(rb.w);
        acc[0] += w3 * bfl(rc.x); acc[1] += w3 * bfh(rc.x);
        acc[2] += w3 * bfl(rc.y); acc[3] += w3 * bfh(rc.y);
        acc[4] += w3 * bfl(rc.z); acc[5] += w3 * bfh(rc.z);
        acc[6] += w3 * bfl(rc.w); acc[7] += w3 * bfh(rc.w);
        acc[0] += w4 * bfl(rd.x); acc[1] += w4 * bfh(rd.x);
        acc[2] += w4 * bfl(rd.y); acc[3] += w4 * bfh(rd.y);
        acc[4] += w4 * bfl(rd.z); acc[5] += w4 * bfh(rd.z);
        acc[6] += w4 * bfl(rd.w); acc[7] += w4 * bfh(rd.w);
    }
    #pragma unroll
    for (int m = 8; m <= 16; m <<= 1) {
        #pragma unroll
        for (int i = 0; i < 8; ++i)
            acc[i] += __shfl_xor(acc[i], m, 64);
    }

    if (r == 0 && valid) {                   // lanes 0..7 and 32..39
        size_t off = ((size_t)node << 6) + (c << 3);
        uint4 rr = *(const uint4*)(featin + off);
        float di = dinv[node];
        uint4 o;
        o.x = pack2(bfl(rr.x) - di * acc[0], bfh(rr.x) - di * acc[1]);
        o.y = pack2(bfl(rr.y) - di * acc[2], bfh(rr.y) - di * acc[3]);
        o.z = pack2(bfl(rr.z) - di * acc[4], bfh(rr.z) - di * acc[5]);
        o.w = pack2(bfl(rr.w) - di * acc[6], bfh(rr.w) - di * acc[7]);
        *(uint4*)(featout + off) = o;
    }
}

// h = th0*xb + th1*f1 + th2*f2 + th3*f3 + th4*f4   (8 elements per thread)
__global__ void k_final(const uint4* __restrict__ xb,
                        const uint4* __restrict__ f1, const uint4* __restrict__ f2,
                        const uint4* __restrict__ f3, const uint4* __restrict__ f4,
                        float4* __restrict__ h4, int n8,
                        float t0, float t1, float t2, float t3, float t4) {
    int i = blockIdx.x * blockDim.x + threadIdx.x;
    if (i >= n8) return;
    uint4 xv = xb[i];
    uint4 a = f1[i], b = f2[i], cc = f3[i], d = f4[i];
    float4 h0, h1;
    h0.x = t0 * bfl(xv.x) + t1 * bfl(a.x) + t2 * bfl(b.x) + t3 * bfl(cc.x) + t4 * bfl(d.x);
    h0.y = t0 * bfh(xv.x) + t1 * bfh(a.x) + t2 * bfh(b.x) + t3 * bfh(cc.x) + t4 * bfh(d.x);
    h0.z = t0 * bfl(xv.y) + t1 * bfl(a.y) + t2 * bfl(b.y) + t3 * bfl(cc.y) + t4 * bfl(d.y);
    h0.w = t0 * bfh(xv.y) + t1 * bfh(a.y) + t2 * bfh(b.y) + t3 * bfh(cc.y) + t4 * bfh(d.y);
    h1.x = t0 * bfl(xv.z) + t1 * bfl(a.z) + t2 * bfl(b.z) + t3 * bfl(cc.z) + t4 * bfl(d.z);
    h1.y = t0 * bfh(xv.z) + t1 * bfh(a.z) + t2 * bfh(b.z) + t3 * bfh(cc.z) + t4 * bfh(d.z);
    h1.z = t0 * bfl(xv.w) + t1 * bfl(a.w) + t2 * bfl(b.w) + t3 * bfl(cc.w) + t4 * bfl(d.w);
    h1.w = t0 * bfh(xv.w) + t1 * bfh(a.w) + t2 * bfh(b.w) + t3 * bfh(cc.w) + t4 * bfh(d.w);
    h4[2 * i] = h0;
    h4[2 * i + 1] = h1;
}

extern "C" void kernel_launch(void* const* d_in, const int* in_sizes, int n_in,
                              void* d_out, int out_size, void* d_ws, size_t ws_size,
                              hipStream_t stream) {
    const float* x  = (const float*)d_in[0];
    const int*   ei = (const int*)d_in[1];   // edge_index [2, E] row-major
    const int N = in_sizes[0] / kF;
    const int E = in_sizes[1] / 2;
    const int* src = ei;
    const int* dst = ei + E;
    float* h = (float*)d_out;

    const int K = (N + NB - 1) >> BSHIFT;         // 391 buckets (K <= KMAX)
    const int cap = 2 * ((E + K - 1) / K);        // per-bucket capacity

    // workspace (~85 MB): gcursor | rp | dinv | ecsr | xb | f1..f4 | pairs
    char* ws = (char*)d_ws;
    size_t off = 0;
    auto carve = [&](size_t bytes) {
        void* p = ws + off;
        off = (off + bytes + 511) & ~(size_t)511;
        return p;
    };
    int*            gcursor = (int*)carve((size_t)K * 4);
    int*            rp      = (int*)carve((size_t)(N + 1) * 4);
    float*          dinv    = (float*)carve((size_t)N * 4);
    int2*           ecsr    = (int2*)carve((size_t)E * 8);
    unsigned short* xb      = (unsigned short*)carve((size_t)N * kF * 2);
    unsigned short* f1      = (unsigned short*)carve((size_t)N * kF * 2);
    unsigned short* f2      = (unsigned short*)carve((size_t)N * kF * 2);
    unsigned short* f3      = (unsigned short*)carve((size_t)N * kF * 2);
    unsigned short* f4      = (unsigned short*)carve((size_t)N * kF * 2);
    unsigned*       pairs   = (unsigned*)carve((size_t)K * cap * 4);

    const float theta[5] = {0.6f, -0.4f, 0.3f, -0.2f, 0.1f};
    const int n8 = N * kF / 8;

    // ---- CSR build (multisplit) with fused x->bf16 convert ----
    hipMemsetAsync(gcursor, 0, (size_t)K * 4, stream);
    k_binA<<<(E + TILE - 1) / TILE, 512, 0, stream>>>(src, dst, pairs, gcursor,
                                                      (const float4*)x, (uint4*)xb,
                                                      n8, E, K, cap);
    k_binB1<<<K, 512, 0, stream>>>(pairs, gcursor, rp, dinv, N, E, K, cap);
    k_binB2<<<K, 512, 0, stream>>>(pairs, gcursor, rp, dinv, ecsr, N, K, cap);

    // ---- 4 gather passes: f_k = L_sym f_{k-1} (bf16 in/out, h deferred) ----
    const int nwaves = (N + 1) / 2;                // 2 nodes per wave
    const int gblocks = (nwaves + 3) / 4;          // 4 waves per 256-thread block
    k_gather<<<gblocks, 256, 0, stream>>>(rp, ecsr, xb, dinv, f1, N);
    k_gather<<<gblocks, 256, 0, stream>>>(rp, ecsr, f1, dinv, f2, N);
    k_gather<<<gblocks, 256, 0, stream>>>(rp, ecsr, f2, dinv, f3, N);
    k_gather<<<gblocks, 256, 0, stream>>>(rp, ecsr, f3, dinv, f4, N);

    // ---- h = th0*xb + sum th_k*f_k (streaming) ----
    k_final<<<(n8 + 255) / 256, 256, 0, stream>>>((const uint4*)xb,
                                                  (const uint4*)f1, (const uint4*)f2,
                                                  (const uint4*)f3, (const uint4*)f4,
                                                  (float4*)h, n8,
                                                  theta[0], theta[1], theta[2],
                                                  theta[3], theta[4]);
}